// Round 6
// baseline (370.162 us; speedup 1.0000x reference)
//
#include <hip/hip_runtime.h>

// AttentionGate: out[b,cf,v] = x[b,cf,v] * sigmoid(Wpsi · relu(Wg·g[b,:,v] + Wx·x[b,:,v]))
// B=2, CF=CG=64, CI=32, SPAT=64^3. fp32.
//
// R7 (resubmit — previous bench was an infra failure, no counters produced).
// Access-PATTERN restructure. R2-R6 exhausted micro-knobs: occupancy (20-70%),
// load width (4/8/16B), manual pipelining, traffic reduction (-20% HBM bytes
// via LDS parking) — ALL land 108-115 µs. Per-wave throughput ~0.44 GB/s =
// ~1 outstanding request despite batched issue. Shared invariant: every wave's
// stream is "<=1KB contiguous, then a 2^20 B jump" — all in-flight requests
// from a wave alias to the same L1 set / L2 slice / new TLB page and
// serialize. Fix: make waves stream CONTIGUOUSLY.
//   - main loop: 512-voxel tile, channels staged 8-at-a-time into LDS with
//     linear coalesced loads (1KB/instr per wave, 4KB-sequential walk);
//     compute reads LDS (v2f, 2-way = free), acc in regs (identical FMA order
//     to R6 -> same numerics).
//   - epilogue: psi redistributed via LDS; each wave then owns 16 whole
//     channel rows and streams them 1KB/instr (x re-read likely L3-hit) ->
//     out writes contiguous, nontemporal.
// LDS 34 KB -> 4 blocks/CU (16 waves/CU, proven sufficient in R2).

#define SPAT 262144        // 64*64*64 voxels per (b,c) plane, 2^18
#define NVOX 524288        // B * SPAT
#define CIN  64
#define COUT 32
#define TILE 512           // voxels per block
#define CH   8             // channels staged per chunk

typedef float v2f __attribute__((ext_vector_type(2)));
typedef float v4f __attribute__((ext_vector_type(4)));

__global__ __launch_bounds__(256) void transpose_w(const float* __restrict__ Wg,
                                                   const float* __restrict__ Wx,
                                                   float* __restrict__ Wcat) {
    int idx = blockIdx.x * 256 + threadIdx.x;   // 0..4095
    int c = idx >> 6;
    int o = idx & 63;
    float v = (o < 32) ? Wg[o * CIN + c] : Wx[(o - 32) * CIN + c];
    Wcat[c * 64 + o] = v;
}

__global__ __launch_bounds__(256, 4) void gate_main(const float* __restrict__ x,
                                                    const float* __restrict__ g,
                                                    const float* __restrict__ Wcat,
                                                    const float* __restrict__ Wpsi,
                                                    float* __restrict__ out) {
    __shared__ float xs[CH][TILE];              // 16 KB
    __shared__ float gs[CH][TILE];              // 16 KB
    __shared__ float psis[TILE];                // 2 KB

    int tid = threadIdx.x;
    int v0 = blockIdx.x * TILE;                 // global voxel base
    int b = v0 >> 18;                           // SPAT = 2^18
    int s0 = v0 & (SPAT - 1);

    const float* __restrict__ xb = x + (size_t)b * CIN * SPAT + s0;
    const float* __restrict__ gb = g + (size_t)b * CIN * SPAT + s0;
    float* __restrict__ ob = out + (size_t)b * CIN * SPAT + s0;

    v2f acc[COUT];
#pragma unroll
    for (int o = 0; o < COUT; ++o) acc[o] = (v2f)(0.0f);

#pragma unroll 1
    for (int c0 = 0; c0 < CIN; c0 += CH) {
        if (c0) __syncthreads();                // previous chunk fully consumed

        // stage CH channel rows of x and g: linear coalesced, 1KB/instr/wave
#pragma unroll
        for (int j = 0; j < 4; ++j) {
            int idx = j * 256 + tid;            // 0..1023 v4f slots
            int ch = idx >> 7;                  // TILE/4 = 128 v4f per row
            int col = idx & 127;
            v4f xv = *((const v4f*)(xb + (size_t)(c0 + ch) * SPAT) + col);
            v4f gv = __builtin_nontemporal_load(
                         (const v4f*)(gb + (size_t)(c0 + ch) * SPAT) + col);
            *((v4f*)&xs[ch][0] + col) = xv;
            *((v4f*)&gs[ch][0] + col) = gv;
        }
        __syncthreads();

        // consume: thread owns voxels (2*tid, 2*tid+1); FMA order == R6
#pragma unroll
        for (int cc = 0; cc < CH; ++cc) {
            v2f xc = *((const v2f*)&xs[cc][0] + tid);   // 2-way, free
            v2f gc = *((const v2f*)&gs[cc][0] + tid);
            const float* w = Wcat + (c0 + cc) * 64;     // wave-uniform scalar
#pragma unroll
            for (int o = 0; o < COUT; ++o) {
                float wg = w[o], wx = w[32 + o];
                acc[o].x = fmaf(wg, gc.x, fmaf(wx, xc.x, acc[o].x));
                acc[o].y = fmaf(wg, gc.y, fmaf(wx, xc.y, acc[o].y));
            }
        }
    }

    // psi for own 2 voxels
    float psx = 0.0f, psy = 0.0f;
#pragma unroll
    for (int o = 0; o < COUT; ++o) {
        float wp = Wpsi[o];
        psx = fmaf(wp, fmaxf(acc[o].x, 0.0f), psx);
        psy = fmaf(wp, fmaxf(acc[o].y, 0.0f), psy);
    }
    v2f psi;
    psi.x = 1.0f / (1.0f + __expf(-psx));
    psi.y = 1.0f / (1.0f + __expf(-psy));
    *((v2f*)psis + tid) = psi;                  // redistribute psi
    __syncthreads();

    // epilogue: wave w owns channels [w*16, w*16+16); streams 1KB/instr
    int w = tid >> 6, l = tid & 63;
    v4f p0 = *((const v4f*)psis + l);           // voxels l*4..+3
    v4f p1 = *((const v4f*)psis + 64 + l);      // voxels 256+l*4..+3
#pragma unroll 1
    for (int i = 0; i < 16; ++i) {
        int c = w * 16 + i;
        const v4f* __restrict__ xr = (const v4f*)(xb + (size_t)c * SPAT);
        v4f* __restrict__ orow = (v4f*)(ob + (size_t)c * SPAT);
        v4f x0 = xr[l];                         // L3/L2-warm re-read, contiguous
        v4f x1 = xr[64 + l];
        __builtin_nontemporal_store(x0 * p0, orow + l);
        __builtin_nontemporal_store(x1 * p1, orow + 64 + l);
    }
}

extern "C" void kernel_launch(void* const* d_in, const int* in_sizes, int n_in,
                              void* d_out, int out_size, void* d_ws, size_t ws_size,
                              hipStream_t stream) {
    const float* x    = (const float*)d_in[0];
    const float* g    = (const float*)d_in[1];
    const float* Wg   = (const float*)d_in[2];
    const float* Wx   = (const float*)d_in[3];
    const float* Wpsi = (const float*)d_in[4];
    float* out  = (float*)d_out;
    float* Wcat = (float*)d_ws;                 // 64*64 floats = 16 KB scratch

    transpose_w<<<16, 256, 0, stream>>>(Wg, Wx, Wcat);
    gate_main<<<NVOX / TILE, 256, 0, stream>>>(x, g, Wcat, Wpsi, out);
}